// Round 24
// baseline (175.106 us; speedup 1.0000x reference)
//
#include <hip/hip_runtime.h>
#include <hip/hip_bf16.h>
#include <stdint.h>

typedef __attribute__((ext_vector_type(8))) short short8;
typedef __attribute__((ext_vector_type(4))) float f32x4;

__device__ __forceinline__ unsigned short f2bf(float f) {
    union { float f; uint32_t u; } v; v.f = f;
    return (unsigned short)((v.u + 0x7FFFu + ((v.u >> 16) & 1u)) >> 16);
}

// Direct global->LDS DMA, 16B per lane. LDS dest = (wave-uniform base) + lane*16.
__device__ __forceinline__ void gload16(const void* g, void* l) {
  __builtin_amdgcn_global_load_lds(
      (const __attribute__((address_space(1))) unsigned int*)g,
      (__attribute__((address_space(3))) unsigned int*)l, 16, 0, 0);
}

// Build W in MFMA-FRAGMENT order with the LINE-COALESCED k-map (R13, unchanged):
//   lane (l15,lhi), elem e holds k = c*32 + (e<4 ? lhi*4+e : 16+lhi*4+(e-4))
//   Wfrag[((ct*6 + c)*64 + lane)*8 + e] = bf16( W[ct*16 + (lane&15)][k] )
// where W[j][k] = kernel[cayley[inv[k>>4], j>>4]][j&15][k&15].
__global__ void build_w_kernel(const float* __restrict__ kern,
                               const int* __restrict__ cayley,
                               const int* __restrict__ inv,
                               unsigned short* __restrict__ Wfrag) {
    int i = blockIdx.x * blockDim.x + threadIdx.x;   // i = ((ct*6+c)*64 + lane)*8 + e
    if (i >= 192 * 192) return;
    int e    = i & 7;
    int lane = (i >> 3) & 63;
    int fc   = i >> 9;            // ct*6 + c
    int ct   = fc / 6, c = fc - ct * 6;
    int j = ct * 16 + (lane & 15);
    int lhi = lane >> 4;
    int k = c * 32 + ((e < 4) ? (lhi * 4 + e) : (16 + lhi * 4 + (e - 4)));
    int h = j >> 4, oc = j & 15;
    int g = k >> 4, ic = k & 15;
    int cidx = cayley[inv[g] * 12 + h];
    Wfrag[i] = f2bf(kern[cidx * 256 + oc * 16 + ic]);
}

// out[n][j] = sum_k x[n][k] * W[j][k] + bias[j]
// R23 = R20 (copy-shaped globals, 168.3us best) with the load path replaced by
// global_load_lds (direct-to-LDS DMA; Common-mistake #1) + counted-vmcnt
// pipeline (never drain to 0 in the loop):
//  - xb: 2-deep UNPADDED ring (16x768B). 768-stride rows would 16-way conflict,
//    and gload_lds writes linearly (m104) -> rule #21: inverse-swizzle the
//    per-lane global SOURCE (u_g = u_lds ^ (row&7), 16B units within 128B
//    windows; 64B lines map to full 64B lines) + same XOR on ds_read side.
//  - per strip: issue 3 DMAs for next strip -> s_waitcnt vmcnt(6) (waits
//    exactly this strip's 3 DMAs; 3 stores + 3 newer DMAs stay in flight) ->
//    raw s_barrier -> frags+cvt+MFMA->ob -> lgkmcnt(0) -> raw s_barrier ->
//    stores. 2 barriers/strip, no vmcnt(0) drain in steady state.
//  - pf strip clamped so EVERY iteration issues exactly 3 (vmcnt count exact).
// W in regs (3 cts/wave), R13 k-map, plain copy-shaped stores, (256,1) cap.
__global__ __launch_bounds__(256, 1) void gemm_kernel(
    const float* __restrict__ x,
    const unsigned short* __restrict__ Wfrag,
    const float* __restrict__ bias,
    float* __restrict__ out, int nstrips, int spb) {
  __shared__ unsigned char xb[2][16 * 768];   // DMA ring, unpadded, source-swizzled
  __shared__ unsigned char ob[16 * 784];      // out bounce, padded rows (R20)
  const int tid  = threadIdx.x;
  const int lane = tid & 63;
  const int wid  = tid >> 6;          // 0..3 -> owns cts [3*wid, 3*wid+3)
  const int l15  = lane & 15;
  const int lhi  = lane >> 4;

  // This wave's 18 W fragments in registers (one-time, L2-resident).
  short8 wf[3][6];
  #pragma unroll
  for (int t = 0; t < 3; ++t)
    #pragma unroll
    for (int c = 0; c < 6; ++c)
      wf[t][c] = *(const short8*)(Wfrag + (((wid * 3 + t) * 6 + c) * 64 + lane) * 8);

  // bias for this lane's 4 output features (oc = lhi*4+r, ct-independent)
  const f32x4 bias4 = *(const f32x4*)(bias + lhi * 4);

  // ---- strip-invariant addressing ----
  // DMA: instruction t covers LDS units [ (wid*3+t)*64 .. +64 ), unit = 16B.
  // Lane's LDS unit L -> row r = L/48, u_lds = L%48; global unit u_g = u_lds^(r&7).
  int gsrc[3];   // per-lane global byte offset within a strip
  #pragma unroll
  for (int t = 0; t < 3; ++t) {
    int L  = ((wid * 3 + t) << 6) + lane;
    int r  = L / 48;
    int u  = L - r * 48;
    int ug = u ^ (r & 7);
    gsrc[t] = r * 768 + (ug << 4);
  }
  // Frag reads from xb: row l15, global unit c*8+lhi (lo) / +4 (hi), swizzled.
  int frl[6], frh[6];
  #pragma unroll
  for (int c = 0; c < 6; ++c) {
    frl[c] = l15 * 768 + (((c * 8 + lhi)     ^ (l15 & 7)) << 4);
    frh[c] = l15 * 768 + (((c * 8 + lhi + 4) ^ (l15 & 7)) << 4);
  }
  // Out bounce (R20 layout, 784-padded): MFMA writes obw, stores read coff -> goff.
  int obw[3], coff[3], goff[3];
  #pragma unroll
  for (int t = 0; t < 3; ++t) {
    obw[t] = l15 * 784 + (wid * 3 + t) * 64 + lhi * 16;
    int idx = ((wid * 3 + t) << 6) + lane;
    int row = idx / 48;
    int cb  = idx - row * 48;
    goff[t] = idx << 4;
    coff[t] = row * 784 + (cb << 4);
  }

  const int s0 = blockIdx.x * spb;
  const int send = min(s0 + spb, nstrips);
  if (s0 >= send) return;

  // Prologue: DMA strip s0 into xb[0]; drain once (also drains wf/bias loads).
  {
    const unsigned char* xs = (const unsigned char*)x + (size_t)s0 * 12288;
    unsigned char* lb = xb[0] + wid * 3 * 1024;
    #pragma unroll
    for (int t = 0; t < 3; ++t) gload16(xs + gsrc[t], lb + t * 1024);
  }
  __syncthreads();   // vmcnt(0)+lgkmcnt(0)+barrier: establishes count invariant

  int cur = 0;
  for (int s = s0; s < send; ++s) {
    // 1) Issue next strip's 3 DMAs into the other buffer (clamped: always 3).
    {
      const int pf = (s + 1 < send) ? (s + 1) : (send - 1);
      const unsigned char* xs = (const unsigned char*)x + (size_t)pf * 12288;
      unsigned char* lb = xb[cur ^ 1] + wid * 3 * 1024;
      #pragma unroll
      for (int t = 0; t < 3; ++t) gload16(xs + gsrc[t], lb + t * 1024);
    }

    // 2) Wait exactly this strip's 3 DMAs (3 stores + 3 newer DMAs in flight).
    asm volatile("s_waitcnt vmcnt(6)" ::: "memory");
    __builtin_amdgcn_sched_barrier(0);
    __builtin_amdgcn_s_barrier();          // all waves' xb[cur] parts landed

    // 3) Frag reads (swizzled) + cvt.
    const unsigned char* xcur = xb[cur];
    short8 abf[6];
    #pragma unroll
    for (int c = 0; c < 6; ++c) {
      f32x4 lo = *(const f32x4*)(xcur + frl[c]);
      f32x4 hi = *(const f32x4*)(xcur + frh[c]);
      short8 v;
      #pragma unroll
      for (int e = 0; e < 4; ++e) {
        v[e]     = (short)f2bf(lo[e]);
        v[e + 4] = (short)f2bf(hi[e]);
      }
      abf[c] = v;
    }

    // 4) MFMA: this wave's 3 cts; results (+bias) into the out-bounce.
    #pragma unroll
    for (int t = 0; t < 3; ++t) {
      f32x4 acc = {0.f, 0.f, 0.f, 0.f};
      #pragma unroll
      for (int c = 0; c < 6; ++c)
        acc = __builtin_amdgcn_mfma_f32_16x16x32_bf16(wf[t][c], abf[c], acc, 0, 0, 0);
      f32x4 res = {acc[0] + bias4[0], acc[1] + bias4[1],
                   acc[2] + bias4[2], acc[3] + bias4[3]};
      *(f32x4*)(ob + obw[t]) = res;
    }
    asm volatile("s_waitcnt lgkmcnt(0)" ::: "memory");
    __builtin_amdgcn_s_barrier();          // ob complete & visible

    // 5) Copy-shaped contiguous stores (fire-and-forget; acks never waited).
    {
      unsigned char* os = (unsigned char*)out + (size_t)s * 12288;
      #pragma unroll
      for (int t = 0; t < 3; ++t) {
        f32x4 v = *(const f32x4*)(ob + coff[t]);
        *(f32x4*)(os + goff[t]) = v;
      }
    }
    cur ^= 1;
  }
}

extern "C" void kernel_launch(void* const* d_in, const int* in_sizes, int n_in,
                              void* d_out, int out_size, void* d_ws, size_t ws_size,
                              hipStream_t stream) {
    const float* x      = (const float*)d_in[0];
    const float* kern   = (const float*)d_in[1];
    const float* bias   = (const float*)d_in[2];
    const int*   cayley = (const int*)d_in[3];
    const int*   inv    = (const int*)d_in[4];
    float* out = (float*)d_out;
    unsigned short* Wfrag = (unsigned short*)d_ws;   // 73728 bytes

    const int nrows = in_sizes[0] / 192;
    const int nstrips = nrows / 16;                  // 32768

    build_w_kernel<<<(192 * 192 + 255) / 256, 256, 0, stream>>>(kern, cayley, inv, Wfrag);

    const int nblocks = 2048;                        // 16 strips per block, no tail
    const int spb     = (nstrips + nblocks - 1) / nblocks;
    gemm_kernel<<<nblocks, 256, 0, stream>>>(x, Wfrag, bias, out, nstrips, spb);
}

// Round 25
// 168.243 us; speedup vs baseline: 1.0408x; 1.0408x over previous
//
#include <hip/hip_runtime.h>
#include <hip/hip_bf16.h>
#include <stdint.h>

typedef __attribute__((ext_vector_type(8))) short short8;
typedef __attribute__((ext_vector_type(4))) float f32x4;

__device__ __forceinline__ unsigned short f2bf(float f) {
    union { float f; uint32_t u; } v; v.f = f;
    return (unsigned short)((v.u + 0x7FFFu + ((v.u >> 16) & 1u)) >> 16);
}

// Build W in MFMA-FRAGMENT order with the LINE-COALESCED k-map (R13, unchanged):
//   lane (l15,lhi), elem e holds k = c*32 + (e<4 ? lhi*4+e : 16+lhi*4+(e-4))
//   Wfrag[((ct*6 + c)*64 + lane)*8 + e] = bf16( W[ct*16 + (lane&15)][k] )
// where W[j][k] = kernel[cayley[inv[k>>4], j>>4]][j&15][k&15].
__global__ void build_w_kernel(const float* __restrict__ kern,
                               const int* __restrict__ cayley,
                               const int* __restrict__ inv,
                               unsigned short* __restrict__ Wfrag) {
    int i = blockIdx.x * blockDim.x + threadIdx.x;   // i = ((ct*6+c)*64 + lane)*8 + e
    if (i >= 192 * 192) return;
    int e    = i & 7;
    int lane = (i >> 3) & 63;
    int fc   = i >> 9;            // ct*6 + c
    int ct   = fc / 6, c = fc - ct * 6;
    int j = ct * 16 + (lane & 15);
    int lhi = lane >> 4;
    int k = c * 32 + ((e < 4) ? (lhi * 4 + e) : (16 + lhi * 4 + (e - 4)));
    int h = j >> 4, oc = j & 15;
    int g = k >> 4, ic = k & 15;
    int cidx = cayley[inv[g] * 12 + h];
    Wfrag[i] = f2bf(kern[cidx * 256 + oc * 16 + ic]);
}

// out[n][j] = sum_k x[n][k] * W[j][k] + bias[j]
// FINAL (R20 restored — session best, 168.3us). Copy-shaped global instrs:
// a strip (16 rows x 768B = 12288B) is contiguous; per block (4 waves):
// 12 x 1KB contiguous loads -> LDS x-bounce (784B-padded rows) -> fragment
// reads + cvt (R13 k-map) -> MFMA (W in regs, 3 cts/wave) -> +bias -> LDS
// out-bounce -> 12 x 1KB contiguous stores. 1-deep prefetch rides through
// compute. (256,1) => 256-VGPR cap (ledger), compiles ~108-140, zero spills.
// Session ledger — positive: plain stores over NT (+22us), copy-shaped
// globals (+9us), W out of vmem stream (~+30us). Null: occupancy 11-47%,
// dbuf/barriers, reg-prefetch depth 1-2, line coverage, ds-batching,
// global_load_lds+counted-vmcnt (-7us). Plateau ~4.8 TB/s effective.
__global__ __launch_bounds__(256, 1) void gemm_kernel(
    const float* __restrict__ x,
    const unsigned short* __restrict__ Wfrag,
    const float* __restrict__ bias,
    float* __restrict__ out, int nstrips, int spb) {
  __shared__ unsigned char xb[16 * 784];   // 12544 B, rows padded 768->784
  __shared__ unsigned char ob[16 * 784];   // 12544 B
  const int tid  = threadIdx.x;
  const int lane = tid & 63;
  const int wid  = tid >> 6;          // 0..3 -> owns cts [3*wid, 3*wid+3)
  const int l15  = lane & 15;
  const int lhi  = lane >> 4;

  // This wave's 18 W fragments in registers (one-time, L2-resident).
  short8 wf[3][6];
  #pragma unroll
  for (int t = 0; t < 3; ++t)
    #pragma unroll
    for (int c = 0; c < 6; ++c)
      wf[t][c] = *(const short8*)(Wfrag + (((wid * 3 + t) * 6 + c) * 64 + lane) * 8);

  // bias for this lane's 4 output features (oc = lhi*4+r, ct-independent)
  const f32x4 bias4 = *(const f32x4*)(bias + lhi * 4);

  // Hoisted strip-invariant addressing.
  int goff[3], coff[3];   // global byte offset within strip; LDS byte offset
  #pragma unroll
  for (int t = 0; t < 3; ++t) {
    int idx = ((wid * 3 + t) << 6) + lane;          // (instr)*64 + lane
    int row = idx / 48;                             // 48 chunks of 16B per 768B row
    int cb  = idx - row * 48;
    goff[t] = idx << 4;
    coff[t] = row * 784 + (cb << 4);
  }
  // Fragment-read offsets into xb: row l15, c-window c: +c*128+lhi*16 (+64).
  const int fbase = l15 * 784 + lhi * 16;
  // Out-bounce write offsets: row l15, float col (3*wid+t)*16 + lhi*4.
  int obw[3];
  #pragma unroll
  for (int t = 0; t < 3; ++t) obw[t] = l15 * 784 + (wid * 3 + t) * 64 + lhi * 16;

  int strip = blockIdx.x * spb;
  const int send = min(strip + spb, nstrips);
  if (strip >= send) return;

  // Prologue: issue strip 0's contiguous loads.
  f32x4 pre[3];
  {
    const unsigned char* xs = (const unsigned char*)x + (size_t)strip * 12288;
    #pragma unroll
    for (int t = 0; t < 3; ++t) pre[t] = *(const f32x4*)(xs + goff[t]);
  }

  while (strip < send) {
    // Deposit this strip's x into the bounce (vmcnt: prefetch loads are
    // OLDER than last strip's stores -> never waits store acks).
    #pragma unroll
    for (int t = 0; t < 3; ++t) *(f32x4*)(xb + coff[t]) = pre[t];
    __syncthreads();

    // Fragment reads + cvt (R13 k-map).
    short8 abf[6];
    #pragma unroll
    for (int c = 0; c < 6; ++c) {
      f32x4 lo = *(const f32x4*)(xb + fbase + c * 128);
      f32x4 hi = *(const f32x4*)(xb + fbase + c * 128 + 64);
      short8 v;
      #pragma unroll
      for (int e = 0; e < 4; ++e) {
        v[e]     = (short)f2bf(lo[e]);
        v[e + 4] = (short)f2bf(hi[e]);
      }
      abf[c] = v;
    }

    // Prefetch next strip's contiguous loads (in flight through MFMA+stores).
    const int nxt = strip + 1;
    if (nxt < send) {
      const unsigned char* xs = (const unsigned char*)x + (size_t)nxt * 12288;
      #pragma unroll
      for (int t = 0; t < 3; ++t) pre[t] = *(const f32x4*)(xs + goff[t]);
    }

    // MFMA: this wave's 3 cts; results (+bias) into the out-bounce.
    #pragma unroll
    for (int t = 0; t < 3; ++t) {
      f32x4 acc = {0.f, 0.f, 0.f, 0.f};
      #pragma unroll
      for (int c = 0; c < 6; ++c)
        acc = __builtin_amdgcn_mfma_f32_16x16x32_bf16(wf[t][c], abf[c], acc, 0, 0, 0);
      f32x4 res = {acc[0] + bias4[0], acc[1] + bias4[1],
                   acc[2] + bias4[2], acc[3] + bias4[3]};
      *(f32x4*)(ob + obw[t]) = res;
    }
    __syncthreads();

    // Contiguous stores: 12 x 1KB per block (3 per wave), copy-shaped.
    {
      unsigned char* os = (unsigned char*)out + (size_t)strip * 12288;
      #pragma unroll
      for (int t = 0; t < 3; ++t) {
        f32x4 v = *(const f32x4*)(ob + coff[t]);
        *(f32x4*)(os + goff[t]) = v;
      }
    }
    __syncthreads();   // bounce buffers free for next strip
    strip = nxt;
  }
}

extern "C" void kernel_launch(void* const* d_in, const int* in_sizes, int n_in,
                              void* d_out, int out_size, void* d_ws, size_t ws_size,
                              hipStream_t stream) {
    const float* x      = (const float*)d_in[0];
    const float* kern   = (const float*)d_in[1];
    const float* bias   = (const float*)d_in[2];
    const int*   cayley = (const int*)d_in[3];
    const int*   inv    = (const int*)d_in[4];
    float* out = (float*)d_out;
    unsigned short* Wfrag = (unsigned short*)d_ws;   // 73728 bytes

    const int nrows = in_sizes[0] / 192;
    const int nstrips = nrows / 16;                  // 32768

    build_w_kernel<<<(192 * 192 + 255) / 256, 256, 0, stream>>>(kern, cayley, inv, Wfrag);

    const int nblocks = 2048;                        // 16 strips per block
    const int spb     = (nstrips + nblocks - 1) / nblocks;
    gemm_kernel<<<nblocks, 256, 0, stream>>>(x, Wfrag, bias, out, nstrips, spb);
}